// Round 13
// baseline (247.319 us; speedup 1.0000x reference)
//
#include <hip/hip_runtime.h>
#include <hip/hip_bf16.h>

#define B 6
#define S 1024
#define H 12
#define DK 64
#define DM 768
#define M (B*S)      // 6144
#define BH (B*H)     // 72

typedef __bf16 bf16;
typedef __attribute__((ext_vector_type(8))) __bf16 bf16x8;
typedef __attribute__((ext_vector_type(4))) float f32x4;

#define MFMA __builtin_amdgcn_mfma_f32_16x16x32_bf16

// 0.125 * log2(e): folded into q so softmax exp becomes a bare v_exp_f32 (2^x)
#define QSCALE 0.18033688011112042f

// single-instruction 2^x (v_exp_f32); avoids __ocml libcall paths
__device__ __forceinline__ float ex2(float x) {
  float r;
  asm("v_exp_f32 %0, %1" : "=v"(r) : "v"(x));
  return r;
}

// lgkm-only barrier: staged LDS visible, but don't drain global stores/loads
__device__ __forceinline__ void lds_barrier() {
  asm volatile("s_waitcnt lgkmcnt(0)" ::: "memory");
  __builtin_amdgcn_s_barrier();
}

// 8 f32 -> bf16x8 (two float4 loads; used in reg-staged prefetch, latency hidden)
__device__ __forceinline__ bf16x8 cvt8(const float* p) {
  float4 u0 = *(const float4*)p;
  float4 u1 = *(const float4*)(p + 4);
  bf16x8 r;
  r[0]=(bf16)u0.x; r[1]=(bf16)u0.y; r[2]=(bf16)u0.z; r[3]=(bf16)u0.w;
  r[4]=(bf16)u1.x; r[5]=(bf16)u1.y; r[6]=(bf16)u1.z; r[7]=(bf16)u1.w;
  return r;
}

// ---------------- prep: weight transpose + bf16 convert only (inputs are
// converted on the fly inside k_proj's staging path now)
__global__ void k_prep(const float* __restrict__ Wq, const float* __restrict__ Wk,
                       const float* __restrict__ Wv, const float* __restrict__ Wo,
                       bf16* __restrict__ wt) {
  int zz = blockIdx.y;
  const float* W = zz==0?Wq : zz==1?Wk : zz==2?Wv : Wo;
  int idx = blockIdx.x*256 + threadIdx.x;   // 0..768*768-1
  int k = idx / DM, n = idx % DM;
  wt[(size_t)zz*DM*DM + (size_t)n*DM + k] = (bf16)W[idx];
}

// ======== GEMM bodies (round-8 proven): 128x128 tile, BK=32, dbuf LDS, reg-staged.
// LDS tile [128 rows][32 k] bf16, read-swizzled: chunk' = chunk ^ ((row>>1)&3).
// ds_write side is LINEAR; swizzle applied by permuting the GLOBAL source chunks.

// ---------------- QKV projection; A read directly from f32 inputs (cvt in
// staging); epilogue scatters q/k/v (kb,vt pre-swizzled; q pre-scaled by QSCALE)
__global__ __launch_bounds__(256, 3) void k_proj(
    const float* __restrict__ Qf, const float* __restrict__ Kf,
    const float* __restrict__ Vf, const bf16* __restrict__ wt,
    const float* __restrict__ bq, const float* __restrict__ bk,
    const float* __restrict__ bv,
    bf16* __restrict__ qb, bf16* __restrict__ kb, bf16* __restrict__ vt) {
  int z = blockIdx.z;
  const float* Xf   = z==0?Qf : z==1?Kf : Vf;
  const float* bias = z==0?bq : z==1?bk : bv;
  const bf16* Wt = wt + (size_t)z*DM*DM;
  int tid = threadIdx.x, lane = tid & 63, w = tid >> 6;
  int wr = w >> 1, wc = w & 1;
  int lr = lane & 15, lg = lane >> 4;
  int m0 = blockIdx.x*128;
  int n0 = blockIdx.y*128;

  __shared__ bf16 As[2][128*32];
  __shared__ bf16 Bs[2][128*32];

  const int srow = tid >> 1;
  const int c0   = (tid & 1) * 2;             // dst chunk pair (16B chunks)
  const int f    = (srow >> 1) & 3;           // swizzle class of this row
  const int sc   = (c0 ^ f) & ~1;             // src chunk pair base (even)
  const bool sw  = (f & 1);                   // swap the two 16B regs
  const float* asrc = Xf + (size_t)(m0 + srow)*DM + sc*8;   // f32 elements
  const bf16*  bsrc = Wt + (size_t)(n0 + srow)*DM + sc*8;
  const int dst0 = srow*32 + c0*8;            // bf16 idx (linear)

  const int fs = (lr >> 1) & 3;
  const int fchunk = (lg ^ fs) * 8;

  f32x4 acc[4][4];
  #pragma unroll
  for (int i=0;i<4;++i)
    #pragma unroll
    for (int j=0;j<4;++j) acc[i][j] = (f32x4){0.f,0.f,0.f,0.f};

  { // prologue: stage tile 0
    bf16x8 a0 = cvt8(asrc);
    bf16x8 a1 = cvt8(asrc + 8);
    bf16x8 b0 = *(const bf16x8*)(bsrc);
    bf16x8 b1 = *(const bf16x8*)(bsrc + 8);
    *(bf16x8*)&As[0][dst0]     = sw ? a1 : a0;
    *(bf16x8*)&As[0][dst0 + 8] = sw ? a0 : a1;
    *(bf16x8*)&Bs[0][dst0]     = sw ? b1 : b0;
    *(bf16x8*)&Bs[0][dst0 + 8] = sw ? b0 : b1;
  }
  lds_barrier();

  for (int t = 0; t < 24; ++t) {
    int cur = t & 1;
    bf16x8 pa0, pa1, pb0, pb1;
    if (t < 23) {
      int k0 = (t+1)*32;
      pa0 = cvt8(asrc + k0);
      pa1 = cvt8(asrc + k0 + 8);
      pb0 = *(const bf16x8*)(bsrc + k0);
      pb1 = *(const bf16x8*)(bsrc + k0 + 8);
    }
    bf16x8 af[4], bfr[4];
    #pragma unroll
    for (int mi=0;mi<4;++mi) af[mi]  = *(const bf16x8*)&As[cur][(wr*64 + mi*16 + lr)*32 + fchunk];
    #pragma unroll
    for (int ni=0;ni<4;++ni) bfr[ni] = *(const bf16x8*)&Bs[cur][(wc*64 + ni*16 + lr)*32 + fchunk];
    #pragma unroll
    for (int mi=0;mi<4;++mi)
      #pragma unroll
      for (int ni=0;ni<4;++ni)
        acc[mi][ni] = MFMA(af[mi], bfr[ni], acc[mi][ni], 0,0,0);
    if (t < 23) {
      *(bf16x8*)&As[cur^1][dst0]     = sw ? pa1 : pa0;
      *(bf16x8*)&As[cur^1][dst0 + 8] = sw ? pa0 : pa1;
      *(bf16x8*)&Bs[cur^1][dst0]     = sw ? pb1 : pb0;
      *(bf16x8*)&Bs[cur^1][dst0 + 8] = sw ? pb0 : pb1;
      lds_barrier();
    }
  }

  int mw = m0 + wr*64, nw = n0 + wc*64;
  #pragma unroll
  for (int ni=0;ni<4;++ni) {
    int n = nw + ni*16 + lr;
    float bs = bias[n];
    int h = n >> 6, d = n & 63;
    #pragma unroll
    for (int mi=0;mi<4;++mi)
      #pragma unroll
      for (int r=0;r<4;++r) {
        int m = mw + mi*16 + lg*4 + r;
        int bb = m >> 10, s = m & 1023;
        float val = acc[mi][ni][r] + bs;
        if (z == 0) {
          qb[((size_t)(bb*H + h)*S + s)*DK + d] = (bf16)(val * QSCALE);
        } else if (z == 1) {
          int dsw = ((((d>>3) ^ (s&7))) << 3) | (d&7);          // slot ^= s&7
          kb[((size_t)(bb*H + h)*S + s)*DK + dsw] = (bf16)val;
        } else {
          int ssw = (s & ~63) | ((((s&63)>>3) ^ (d&7)) << 3) | (s&7); // slot ^= d&7
          vt[((size_t)(bb*H + h)*DK + d)*S + ssw] = (bf16)val;
        }
      }
  }
}

// ---------------- out projection + bias + residual -> x (f32), same tiled body
__global__ __launch_bounds__(256, 3) void k_oproj(
    const bf16* __restrict__ ctx, const bf16* __restrict__ wto,
    const float* __restrict__ bo, const float* __restrict__ res,
    float* __restrict__ x) {
  int tid = threadIdx.x, lane = tid & 63, w = tid >> 6;
  int wr = w >> 1, wc = w & 1;
  int lr = lane & 15, lg = lane >> 4;
  int m0 = blockIdx.x*128;
  int n0 = blockIdx.y*128;

  __shared__ bf16 As[2][128*32];
  __shared__ bf16 Bs[2][128*32];

  const int srow = tid >> 1;
  const int c0   = (tid & 1) * 2;
  const int f    = (srow >> 1) & 3;
  const int sc   = (c0 ^ f) & ~1;
  const bool sw  = (f & 1);
  const bf16* asrc = ctx + (size_t)(m0 + srow)*DM + sc*8;
  const bf16* bsrc = wto + (size_t)(n0 + srow)*DM + sc*8;
  const int dst0 = srow*32 + c0*8;
  const int fs = (lr >> 1) & 3;
  const int fchunk = (lg ^ fs) * 8;

  f32x4 acc[4][4];
  #pragma unroll
  for (int i=0;i<4;++i)
    #pragma unroll
    for (int j=0;j<4;++j) acc[i][j] = (f32x4){0.f,0.f,0.f,0.f};

  {
    bf16x8 a0 = *(const bf16x8*)(asrc);
    bf16x8 a1 = *(const bf16x8*)(asrc + 8);
    bf16x8 b0 = *(const bf16x8*)(bsrc);
    bf16x8 b1 = *(const bf16x8*)(bsrc + 8);
    *(bf16x8*)&As[0][dst0]     = sw ? a1 : a0;
    *(bf16x8*)&As[0][dst0 + 8] = sw ? a0 : a1;
    *(bf16x8*)&Bs[0][dst0]     = sw ? b1 : b0;
    *(bf16x8*)&Bs[0][dst0 + 8] = sw ? b0 : b1;
  }
  lds_barrier();

  for (int t = 0; t < 24; ++t) {
    int cur = t & 1;
    bf16x8 pa0, pa1, pb0, pb1;
    if (t < 23) {
      int k0 = (t+1)*32;
      pa0 = *(const bf16x8*)(asrc + k0);
      pa1 = *(const bf16x8*)(asrc + k0 + 8);
      pb0 = *(const bf16x8*)(bsrc + k0);
      pb1 = *(const bf16x8*)(bsrc + k0 + 8);
    }
    bf16x8 af[4], bfr[4];
    #pragma unroll
    for (int mi=0;mi<4;++mi) af[mi]  = *(const bf16x8*)&As[cur][(wr*64 + mi*16 + lr)*32 + fchunk];
    #pragma unroll
    for (int ni=0;ni<4;++ni) bfr[ni] = *(const bf16x8*)&Bs[cur][(wc*64 + ni*16 + lr)*32 + fchunk];
    #pragma unroll
    for (int mi=0;mi<4;++mi)
      #pragma unroll
      for (int ni=0;ni<4;++ni)
        acc[mi][ni] = MFMA(af[mi], bfr[ni], acc[mi][ni], 0,0,0);
    if (t < 23) {
      *(bf16x8*)&As[cur^1][dst0]     = sw ? pa1 : pa0;
      *(bf16x8*)&As[cur^1][dst0 + 8] = sw ? pa0 : pa1;
      *(bf16x8*)&Bs[cur^1][dst0]     = sw ? pb1 : pb0;
      *(bf16x8*)&Bs[cur^1][dst0 + 8] = sw ? pb0 : pb1;
      lds_barrier();
    }
  }

  int mw = m0 + wr*64, nw = n0 + wc*64;
  #pragma unroll
  for (int ni=0;ni<4;++ni) {
    int n = nw + ni*16 + lr;
    float bb = bo[n];
    #pragma unroll
    for (int mi=0;mi<4;++mi)
      #pragma unroll
      for (int r=0;r<4;++r) {
        int m = mw + mi*16 + lg*4 + r;
        x[(size_t)m*DM + n] = acc[mi][ni][r] + bb + res[(size_t)m*DM + n];
      }
  }
}

__device__ __forceinline__ unsigned pk2(float a, float b) {
  union { bf16 h[2]; unsigned u; } x;
  x.h[0] = (bf16)a; x.h[1] = (bf16)b;
  return x.u;
}

// ---------------- fused attention (round-8 structure, v_exp, nt attn stores):
// Block = (bh, 64 q-rows), 4 waves x 16 rows. K/V tiles (64k x 64dk) double-
// buffered in LDS, staged by reg round-trip; lgkm-only barriers.
// Swapped QK^T: mfma(A=K, B=Q) -> lane(lr,lg) holds p[k=lg*4+r][q=lr].
__global__ __launch_bounds__(256, 4) void k_fattn(
    const bf16* __restrict__ qb, const bf16* __restrict__ kb,
    const bf16* __restrict__ vt, const unsigned char* __restrict__ mask,
    float* __restrict__ attn, bf16* __restrict__ ctx) {
  int lin = blockIdx.x + 16*blockIdx.y;   // 0..1151
  int xcd  = lin & 7;
  int slot = lin >> 3;
  int qt   = slot & 15;
  int bh   = xcd*9 + (slot >> 4);         // bijective remap: head locality per XCD
  int b = bh / H, h = bh - b*H;
  int tid = threadIdx.x, lane = tid & 63, w = tid >> 6;
  int lr = lane & 15, lg = lane >> 4;
  int q0 = qt*64 + w*16;

  __shared__ bf16 Kb[2][4096];      // [64 k][64 dk] swizzled, 8KB each
  __shared__ bf16 Vb[2][4096];      // [64 dk][64 k] swizzled, 8KB each
  __shared__ bf16 pt[4][2][512];    // per-wave P ping-pong tiles, 1KB each

  const bf16* qbase = qb + ((size_t)bh*S + q0 + lr)*DK + lg*8;
  bf16x8 qa0 = *(const bf16x8*)(qbase);
  bf16x8 qa1 = *(const bf16x8*)(qbase + 32);

  const char* kg = (const char*)(kb + (size_t)bh*S*DK);   // 8KB contiguous per tile
  const char* vg = (const char*)(vt + (size_t)bh*DK*S);   // rows 2048B apart
  const unsigned char* mrow = mask + ((size_t)b*S + q0 + lr)*S;
  float* abase = attn + ((size_t)bh*S + q0 + lr)*S;

  const int koff0 = w*2048 + lane*16, koff1 = koff0 + 1024;
  const int kd0 = w*1024 + lane*8,    kd1 = kd0 + 512;
  const int vrow0 = w*16 + (lane>>3), vrow1 = vrow0 + 8;
  const int vcb = (lane&7)*16;
  const int vd0 = vrow0*64 + (lane&7)*8, vd1 = vd0 + 512;

  const int krow = lr*64;
  const int kf0o = krow + ((lg ^ (lr&7))<<3);
  const int kf1o = krow + (((4+lg) ^ (lr&7))<<3);
  const int swz  = (lr & 3) << 4;

  // ================= PASS 1: row sums =================
  {
    bf16x8 a0 = *(const bf16x8*)(kg + koff0);
    bf16x8 a1 = *(const bf16x8*)(kg + koff1);
    *(bf16x8*)&Kb[0][kd0] = a0;
    *(bf16x8*)&Kb[0][kd1] = a1;
  }
  uchar4 mkn[4];
  #pragma unroll
  for (int i=0;i<4;++i) mkn[i] = *(const uchar4*)(mrow + i*16 + lg*4);
  lds_barrier();

  float sum = 0.f;
  for (int t = 0; t < 16; ++t) {
    int cur = t & 1;
    uchar4 mkc[4];
    #pragma unroll
    for (int i=0;i<4;++i) mkc[i] = mkn[i];
    bf16x8 kn0, kn1;
    if (t < 15) {
      kn0 = *(const bf16x8*)(kg + (t+1)*8192 + koff0);
      kn1 = *(const bf16x8*)(kg + (t+1)*8192 + koff1);
      #pragma unroll
      for (int i=0;i<4;++i) mkn[i] = *(const uchar4*)(mrow + (t+1)*64 + i*16 + lg*4);
    }
    #pragma unroll
    for (int i=0;i<4;++i) {
      bf16x8 kf0 = *(const bf16x8*)&Kb[cur][i*1024 + kf0o];
      bf16x8 kf1 = *(const bf16x8*)&Kb[cur][i*1024 + kf1o];
      f32x4 sc = {0.f,0.f,0.f,0.f};
      sc = MFMA(kf0, qa0, sc, 0,0,0);
      sc = MFMA(kf1, qa1, sc, 0,0,0);
      sum += mkc[i].x ? 0.f : ex2(sc[0]);
      sum += mkc[i].y ? 0.f : ex2(sc[1]);
      sum += mkc[i].z ? 0.f : ex2(sc[2]);
      sum += mkc[i].w ? 0.f : ex2(sc[3]);
    }
    if (t < 15) {
      *(bf16x8*)&Kb[cur^1][kd0] = kn0;
      *(bf16x8*)&Kb[cur^1][kd1] = kn1;
    }
    lds_barrier();
  }
  sum += __shfl_xor(sum, 16);
  sum += __shfl_xor(sum, 32);
  float inv = 1.f / sum;

  // ================= PASS 2: attn write + PV =================
  f32x4 cacc[4];
  #pragma unroll
  for (int d=0;d<4;++d) cacc[d] = (f32x4){0.f,0.f,0.f,0.f};

  {
    bf16x8 a0 = *(const bf16x8*)(kg + koff0);
    bf16x8 a1 = *(const bf16x8*)(kg + koff1);
    bf16x8 b0 = *(const bf16x8*)(vg + (size_t)vrow0*2048 + vcb);
    bf16x8 b1 = *(const bf16x8*)(vg + (size_t)vrow1*2048 + vcb);
    *(bf16x8*)&Kb[0][kd0] = a0;
    *(bf16x8*)&Kb[0][kd1] = a1;
    *(bf16x8*)&Vb[0][vd0] = b0;
    *(bf16x8*)&Vb[0][vd1] = b1;
    #pragma unroll
    for (int i=0;i<4;++i) mkn[i] = *(const uchar4*)(mrow + i*16 + lg*4);
  }
  lds_barrier();

  for (int t = 0; t < 16; ++t) {
    int cur = t & 1;
    uchar4 mkc[4];
    #pragma unroll
    for (int i=0;i<4;++i) mkc[i] = mkn[i];
    bf16x8 kn0, kn1, vn0, vn1;
    if (t < 15) {
      kn0 = *(const bf16x8*)(kg + (t+1)*8192 + koff0);
      kn1 = *(const bf16x8*)(kg + (t+1)*8192 + koff1);
      vn0 = *(const bf16x8*)(vg + (size_t)vrow0*2048 + (t+1)*128 + vcb);
      vn1 = *(const bf16x8*)(vg + (size_t)vrow1*2048 + (t+1)*128 + vcb);
      #pragma unroll
      for (int i=0;i<4;++i) mkn[i] = *(const uchar4*)(mrow + (t+1)*64 + i*16 + lg*4);
    }
    #pragma unroll
    for (int u = 0; u < 2; ++u) {
      char* buf = (char*)&pt[w][u][0];
      #pragma unroll
      for (int half = 0; half < 2; ++half) {
        int i = u*2 + half;
        bf16x8 kf0 = *(const bf16x8*)&Kb[cur][i*1024 + kf0o];
        bf16x8 kf1 = *(const bf16x8*)&Kb[cur][i*1024 + kf1o];
        f32x4 sc = {0.f,0.f,0.f,0.f};
        sc = MFMA(kf0, qa0, sc, 0,0,0);
        sc = MFMA(kf1, qa1, sc, 0,0,0);
        float p0 = mkc[i].x ? 0.f : ex2(sc[0])*inv;
        float p1 = mkc[i].y ? 0.f : ex2(sc[1])*inv;
        float p2 = mkc[i].z ? 0.f : ex2(sc[2])*inv;
        float p3 = mkc[i].w ? 0.f : ex2(sc[3])*inv;
        // attn is write-once, never re-read: non-temporal keeps K/V in L2
        __builtin_nontemporal_store((f32x4){p0,p1,p2,p3},
                                    (f32x4*)(abase + t*64 + i*16 + lg*4));
        uint2 pw2; pw2.x = pk2(p0,p1); pw2.y = pk2(p2,p3);
        *(uint2*)(buf + lr*64 + ((half*32 + lg*8) ^ swz)) = pw2;
      }
      bf16x8 pa = *(const bf16x8*)(buf + lr*64 + ((lg*16) ^ swz));
      #pragma unroll
      for (int dd=0; dd<4; ++dd) {
        bf16x8 vf = *(const bf16x8*)&Vb[cur][dd*1024 + lr*64 + ((((u*4+lg) ^ (lr&7)))<<3)];
        cacc[dd] = MFMA(pa, vf, cacc[dd], 0,0,0);
      }
    }
    if (t < 15) {
      *(bf16x8*)&Kb[cur^1][kd0] = kn0;
      *(bf16x8*)&Kb[cur^1][kd1] = kn1;
      *(bf16x8*)&Vb[cur^1][vd0] = vn0;
      *(bf16x8*)&Vb[cur^1][vd1] = vn1;
    }
    lds_barrier();
  }

  #pragma unroll
  for (int d=0;d<4;++d)
    #pragma unroll
    for (int r=0;r<4;++r)
      ctx[((size_t)b*S + q0 + lg*4 + r)*DM + h*DK + d*16 + lr] = (bf16)cacc[d][r];
}

// ---------------- layernorm rows of 768 -> d_out
__global__ void k_ln(const float* __restrict__ x, const float* __restrict__ gamma,
                     const float* __restrict__ beta, float* __restrict__ out) {
  int row = blockIdx.x; int tid = threadIdx.x;
  const float* xr = x + (size_t)row*DM;
  float v0 = xr[tid], v1 = xr[tid+256], v2 = xr[tid+512];
  float s = v0+v1+v2, ss = v0*v0+v1*v1+v2*v2;
  #pragma unroll
  for (int off=32; off; off>>=1){ s += __shfl_xor(s,off); ss += __shfl_xor(ss,off); }
  __shared__ float sm[8];
  int w = tid>>6;
  if ((tid&63)==0){ sm[w]=s; sm[4+w]=ss; }
  __syncthreads();
  s = sm[0]+sm[1]+sm[2]+sm[3]; ss = sm[4]+sm[5]+sm[6]+sm[7];
  float mean = s * (1.f/DM);
  float var = ss * (1.f/DM) - mean*mean;
  float rstd = rsqrtf(var + 1e-5f);
  out[(size_t)row*DM + tid]     = (v0-mean)*rstd*gamma[tid]     + beta[tid];
  out[(size_t)row*DM + tid+256] = (v1-mean)*rstd*gamma[tid+256] + beta[tid+256];
  out[(size_t)row*DM + tid+512] = (v2-mean)*rstd*gamma[tid+512] + beta[tid+512];
}

extern "C" void kernel_launch(void* const* d_in, const int* in_sizes, int n_in,
                              void* d_out, int out_size, void* d_ws, size_t ws_size,
                              hipStream_t stream) {
  const float* Q  = (const float*)d_in[0];
  const float* K  = (const float*)d_in[1];
  const float* V  = (const float*)d_in[2];
  const unsigned char* mask = (const unsigned char*)d_in[3];
  const float* Wq = (const float*)d_in[4];
  const float* bq = (const float*)d_in[5];
  const float* Wk = (const float*)d_in[6];
  const float* bk = (const float*)d_in[7];
  const float* Wv = (const float*)d_in[8];
  const float* bv = (const float*)d_in[9];
  const float* Wo = (const float*)d_in[10];
  const float* bo = (const float*)d_in[11];
  const float* gamma = (const float*)d_in[12];
  const float* beta  = (const float*)d_in[13];

  char* ws = (char*)d_ws;
  bf16* wt  = (bf16*)(ws + 0);            // [4][768][768]        4,718,592 B
  float* x  = (float*)(ws + 4718592);     // [6144][768] f32     18,874,368 B
  bf16* qb  = (bf16*)(ws + 33030144);     // [72][1024][64] q*QSCALE
  bf16* kb  = (bf16*)(ws + 42467328);     // [72][1024][64] swz   9,437,184 B
  bf16* vt  = (bf16*)(ws + 51904512);     // [72][64][1024] swz   9,437,184 B
  bf16* ctx = (bf16*)(ws + 61341696);     // [6][1024][768]       9,437,184 B

  float* out  = (float*)d_out;                   // [6][1024][768]
  float* attn = out + (size_t)B*S*DM;            // [6][12][1024][1024]

  k_prep  <<<dim3(2304,4),  256, 0, stream>>>(Wq,Wk,Wv,Wo,wt);
  k_proj  <<<dim3(48,6,3),  256, 0, stream>>>(Q,K,V,wt,bq,bk,bv,qb,kb,vt);
  k_fattn <<<dim3(16,BH),   256, 0, stream>>>(qb,kb,vt,mask,attn,ctx);
  k_oproj <<<dim3(48,6),    256, 0, stream>>>(ctx, wt + (size_t)3*DM*DM, bo, Q, x);
  k_ln    <<<dim3(M),       256, 0, stream>>>(x,gamma,beta,out);
}